// Round 8
// baseline (817.263 us; speedup 1.0000x reference)
//
#include <hip/hip_runtime.h>

#define N_POINTS 100000
#define N_PAIRS  50000
#define K_OFFSETS 27
#define C 128
#define WPAD 136   // 128 + 8 bf16 pad; LDS row stride 272B

// CSR-ordered msg: conv scatters rows to per-point slots, gather reads streams.
// Per-chunk exact CSR (chunk = G consecutive k): regions allocated by wave-scan
// + one atomicAdd per wave (order irrelevant, only per-point contiguity matters).
#define NCH_MAX 7          // chunk-meta arrays sized for up to 7 chunks (G>=4)

// XCD-partitioned passes (round-2 proven): group g = blockIdx.x % 8 owns points
// [g*12500, (g+1)*12500) so its counter lines live in ONE XCD's L2.
#define CSR_GROUPS 8
#define CSR_BPG 128

typedef __attribute__((ext_vector_type(8))) short short8;
typedef __attribute__((ext_vector_type(4))) float floatx4;

__device__ inline unsigned short f2bf(float f) {
  unsigned int u = __float_as_uint(f);
  return (unsigned short)((u + 0x7FFFu + ((u >> 16) & 1u)) >> 16);  // RNE
}
__device__ inline float bf2f(unsigned int lo16) {
  return __uint_as_float(lo16 << 16);
}

// WT[k][d*C + c] = bf16(W[k][c][d])  -- natural order for BOTH layers
__global__ __launch_bounds__(256) void prep_w_kernel(
    const float* __restrict__ W0, const float* __restrict__ W1,
    unsigned short* __restrict__ WT0, unsigned short* __restrict__ WT1) {
  int i = blockIdx.x * 256 + threadIdx.x;
  const int per = K_OFFSETS * C * C;
  if (i >= 2 * per) return;
  const float* W = (i < per) ? W0 : W1;
  unsigned short* WT = (i < per) ? WT0 : WT1;
  int r = (i < per) ? i : i - per;
  int k = r / (C * C);
  int q = r % (C * C);
  int d = q / C;
  int c = q % C;
  WT[k * C * C + d * C + c] = f2bf(W[k * C * C + c * C + d]);
}

// xb = bf16(features); out = broadcast(b0) only on the fallback path
__global__ __launch_bounds__(256) void prep_x_kernel(
    const float* __restrict__ features, const float* __restrict__ b0,
    unsigned short* __restrict__ xb, float* __restrict__ out, int write_out) {
  int i = (blockIdx.x * 256 + threadIdx.x) * 4;
  if (i >= N_POINTS * C) return;
  float4 f = *(const float4*)&features[i];
  ushort4 u;
  u.x = f2bf(f.x); u.y = f2bf(f.y); u.z = f2bf(f.z); u.w = f2bf(f.w);
  *(ushort4*)&xb[i] = u;
  if (write_out) {
    float4 b = *(const float4*)&b0[i & 127];
    *(float4*)&out[i] = b;
  }
}

__global__ __launch_bounds__(256) void zero_meta_kernel(
    int* __restrict__ countc, int* __restrict__ ccur) {
  int i = blockIdx.x * 256 + threadIdx.x;
  if (i < NCH_MAX * N_POINTS) countc[i] = 0;
  if (i < NCH_MAX) ccur[i] = 0;
}

// Pass 1: per-(chunk,point) entry counts. XCD-partitioned over point ranges.
// chunk index c = flat / (N_PAIRS*G)  (== (flat/N_PAIRS)/G).
__global__ __launch_bounds__(256) void count_kernel(
    const int* __restrict__ out_map, int* __restrict__ countc, int PG) {
  const int grp = blockIdx.x & (CSR_GROUPS - 1);
  const int blk = blockIdx.x >> 3;
  const int lo = grp * (N_POINTS / CSR_GROUPS);
  const int hi = lo + (N_POINTS / CSR_GROUPS);
  const int total4 = K_OFFSETS * N_PAIRS / 4;   // 337500
  for (int i4 = blk * 256 + (int)threadIdx.x; i4 < total4; i4 += CSR_BPG * 256) {
    int4 o4 = *(const int4*)&out_map[i4 * 4];
    int o[4] = {o4.x, o4.y, o4.z, o4.w};
#pragma unroll
    for (int j = 0; j < 4; ++j) {
      if (o[j] >= lo && o[j] < hi) {
        int c = (i4 * 4 + j) / PG;
        atomicAdd(&countc[c * N_POINTS + o[j]], 1);
      }
    }
  }
}

// Pass 2: allocate per-point contiguous regions in msg2 (chunk-local).
// Wave-level inclusive scan of counts + one atomicAdd per wave on the chunk
// cursor; region order is arbitrary, only contiguity per point matters.
// startc = region base; cursA/cursB = live cursors for conv (layer 0/1).
__global__ __launch_bounds__(256) void alloc_kernel(
    const int* __restrict__ countc, int* __restrict__ startc,
    int* __restrict__ cursA, int* __restrict__ cursB, int* __restrict__ ccur) {
  const int c = blockIdx.y;
  const int oi = blockIdx.x * 256 + (int)threadIdx.x;
  const int lane = threadIdx.x & 63;
  int cnt = (oi < N_POINTS) ? countc[c * N_POINTS + oi] : 0;
  int x = cnt;
#pragma unroll
  for (int off = 1; off < 64; off <<= 1) {
    int y = __shfl_up(x, off);
    if (lane >= off) x += y;
  }
  int wtot = __shfl(x, 63);
  int base = 0;
  if (lane == 63) base = atomicAdd(&ccur[c], wtot);
  base = __shfl(base, 63);
  int s = base + x - cnt;   // exclusive prefix within wave
  if (oi < N_POINTS) {
    startc[c * N_POINTS + oi] = s;
    cursA[c * N_POINTS + oi] = s;
    cursB[c * N_POINTS + oi] = s;
  }
}

// Phase A (CSR variant): same MFMA core as the verified conv_msg; the store
// scatters each 256B row to its CSR slot: sl = atomicAdd(curs[o]) (one lane per
// 16-lane group, broadcast via shfl). Scattered FULL-row writes have no line
// RMW; the latency is fire-and-forget. curs is pre-offset to the chunk.
__global__ __launch_bounds__(256, 4) void conv_msg_csr_kernel(
    const unsigned short* __restrict__ xb, const unsigned short* __restrict__ wbt,
    const int* __restrict__ in_map, const int* __restrict__ out_map,
    int* __restrict__ curs, unsigned short* __restrict__ msg2, int k0) {
  __shared__ unsigned short Wlds[C * WPAD];

  const int k = k0 + blockIdx.y;
  const int pairBase = blockIdx.x * 128;
  const int tid = threadIdx.x;

  const unsigned short* wk = wbt + k * C * C;
#pragma unroll
  for (int it = 0; it < 8; ++it) {
    int t = tid + it * 256;
    int row = t >> 4;
    int col = (t & 15) << 3;
    *(uint4*)&Wlds[row * WPAD + col] = *(const uint4*)&wk[row * C + col];
  }
  __syncthreads();

  const int wave = tid >> 6;
  const int lane = tid & 63;
  const int l15 = lane & 15;
  const int kg = lane >> 4;
  const int pair0 = pairBase + wave * 32;        // this wave's 32 pairs (2 tiles)

  const int prA0 = pair0 + l15;
  const int prA1 = pair0 + 16 + l15;
  const int inIdx0 = (prA0 < N_PAIRS) ? in_map[k * N_PAIRS + prA0] : 0;
  const int inIdx1 = (prA1 < N_PAIRS) ? in_map[k * N_PAIRS + prA1] : 0;
  const unsigned short* arow0 = xb + (size_t)inIdx0 * C + kg * 8;
  const unsigned short* arow1 = xb + (size_t)inIdx1 * C + kg * 8;

  floatx4 acc0[8], acc1[8];
#pragma unroll
  for (int nt = 0; nt < 8; ++nt) {
    acc0[nt] = (floatx4){0.f, 0.f, 0.f, 0.f};
    acc1[nt] = (floatx4){0.f, 0.f, 0.f, 0.f};
  }

#pragma unroll
  for (int kk = 0; kk < 4; ++kk) {
    short8 a0 = *(const short8*)(arow0 + kk * 32);
    short8 a1 = *(const short8*)(arow1 + kk * 32);
    const unsigned short* bbase = &Wlds[l15 * WPAD + kk * 32 + kg * 8];
#pragma unroll
    for (int nt = 0; nt < 8; ++nt) {
      short8 b = *(const short8*)(bbase + nt * 16 * WPAD);
      acc0[nt] = __builtin_amdgcn_mfma_f32_16x16x32_bf16(a0, b, acc0[nt], 0, 0, 0);
      acc1[nt] = __builtin_amdgcn_mfma_f32_16x16x32_bf16(a1, b, acc1[nt], 0, 0, 0);
    }
  }

#pragma unroll
  for (int i = 0; i < 4; ++i) {
    int pr0 = pair0 + kg * 4 + i;
    if (pr0 < N_PAIRS) {
      int o = out_map[k * N_PAIRS + pr0];
      int sl = 0;
      if (l15 == 0) sl = atomicAdd(&curs[o], 1);
      sl = __shfl(sl, kg * 16);
      unsigned short* row = msg2 + (size_t)sl * C;
      uint4 v;
      v.x = (unsigned int)f2bf(acc0[0][i]) | ((unsigned int)f2bf(acc0[1][i]) << 16);
      v.y = (unsigned int)f2bf(acc0[2][i]) | ((unsigned int)f2bf(acc0[3][i]) << 16);
      v.z = (unsigned int)f2bf(acc0[4][i]) | ((unsigned int)f2bf(acc0[5][i]) << 16);
      v.w = (unsigned int)f2bf(acc0[6][i]) | ((unsigned int)f2bf(acc0[7][i]) << 16);
      *(uint4*)(row + l15 * 8) = v;
    }
    int pr1 = pair0 + 16 + kg * 4 + i;
    if (pr1 < N_PAIRS) {
      int o = out_map[k * N_PAIRS + pr1];
      int sl = 0;
      if (l15 == 0) sl = atomicAdd(&curs[o], 1);
      sl = __shfl(sl, kg * 16);
      unsigned short* row = msg2 + (size_t)sl * C;
      uint4 v;
      v.x = (unsigned int)f2bf(acc1[0][i]) | ((unsigned int)f2bf(acc1[1][i]) << 16);
      v.y = (unsigned int)f2bf(acc1[2][i]) | ((unsigned int)f2bf(acc1[3][i]) << 16);
      v.z = (unsigned int)f2bf(acc1[4][i]) | ((unsigned int)f2bf(acc1[5][i]) << 16);
      v.w = (unsigned int)f2bf(acc1[6][i]) | ((unsigned int)f2bf(acc1[7][i]) << 16);
      *(uint4*)(row + l15 * 8) = v;
    }
  }
}

// Phase B (CSR variant): one wave per point; msg rows for this point are
// CONTIGUOUS [s0, s0+cnt) -> pure streaming reads. No idxbuf, no ballot, no LDS,
// no barriers. Lane owns channels c0, c0+16 (uint at byte lane*4 of each row).
// init_mode: 0 = resume from out, 1 = bias, 2 = bias + residual
// fin_mode:  0 = write out (fp32), 1 = relu -> x1b (bf16)
__global__ __launch_bounds__(256) void gather_csr_kernel(
    const unsigned short* __restrict__ msg2, const int* __restrict__ countc,
    const int* __restrict__ startc, const float* __restrict__ bias,
    const float* __restrict__ features, float* __restrict__ out,
    unsigned short* __restrict__ x1b, int init_mode, int fin_mode) {
  const int wave = threadIdx.x >> 6;
  const int lane = threadIdx.x & 63;
  const int oi = blockIdx.x * 4 + wave;

  const int c0 = ((2 * lane) & 7) * 16 + (lane >> 2);
  const int c1 = c0 + 16;
  const size_t base = (size_t)oi * C;

  float a0, a1;
  if (init_mode == 1)      { a0 = bias[c0]; a1 = bias[c1]; }
  else if (init_mode == 2) { a0 = bias[c0] + features[base + c0];
                             a1 = bias[c1] + features[base + c1]; }
  else                     { a0 = out[base + c0]; a1 = out[base + c1]; }

  const int cnt = countc[oi];
  const int s0 = startc[oi];
  const unsigned short* mb = msg2 + (size_t)s0 * C + 2 * lane;

  int t = 0;
  for (; t + 4 <= cnt; t += 4) {
    unsigned int v0 = *(const unsigned int*)(mb + (t + 0) * C);
    unsigned int v1 = *(const unsigned int*)(mb + (t + 1) * C);
    unsigned int v2 = *(const unsigned int*)(mb + (t + 2) * C);
    unsigned int v3 = *(const unsigned int*)(mb + (t + 3) * C);
    a0 += bf2f(v0 & 0xffffu) + bf2f(v1 & 0xffffu) + bf2f(v2 & 0xffffu) + bf2f(v3 & 0xffffu);
    a1 += bf2f(v0 >> 16) + bf2f(v1 >> 16) + bf2f(v2 >> 16) + bf2f(v3 >> 16);
  }
  for (; t < cnt; ++t) {
    unsigned int v = *(const unsigned int*)(mb + t * C);
    a0 += bf2f(v & 0xffffu);
    a1 += bf2f(v >> 16);
  }

  if (fin_mode == 1) {
    x1b[base + c0] = f2bf(fmaxf(a0, 0.f));
    x1b[base + c1] = f2bf(fmaxf(a1, 0.f));
  } else {
    out[base + c0] = a0;
    out[base + c1] = a1;
  }
}

// ---------------- fallback (atomic path, small ws, natural WT) ----------------
__global__ __launch_bounds__(256) void mid_kernel(
    const float* __restrict__ features, const float* __restrict__ b1,
    float* __restrict__ out, unsigned short* __restrict__ x1b) {
  int i = (blockIdx.x * 256 + threadIdx.x) * 4;
  if (i >= N_POINTS * C) return;
  float4 y = *(const float4*)&out[i];
  ushort4 u;
  u.x = f2bf(fmaxf(y.x, 0.f));
  u.y = f2bf(fmaxf(y.y, 0.f));
  u.z = f2bf(fmaxf(y.z, 0.f));
  u.w = f2bf(fmaxf(y.w, 0.f));
  *(ushort4*)&x1b[i] = u;
  float4 f = *(const float4*)&features[i];
  float4 b = *(const float4*)&b1[i & 127];
  float4 o;
  o.x = f.x + b.x; o.y = f.y + b.y; o.z = f.z + b.z; o.w = f.w + b.w;
  *(float4*)&out[i] = o;
}

__global__ __launch_bounds__(256, 4) void conv_atomic_kernel(
    const unsigned short* __restrict__ xb, const unsigned short* __restrict__ wbt,
    const int* __restrict__ in_map, const int* __restrict__ out_map,
    float* __restrict__ out) {
  __shared__ unsigned short Wlds[C * WPAD];
  const int k = blockIdx.y;
  const int pairBase = blockIdx.x * 64;
  const int tid = threadIdx.x;
  const unsigned short* wk = wbt + k * C * C;
#pragma unroll
  for (int it = 0; it < 8; ++it) {
    int t = tid + it * 256;
    int row = t >> 4;
    int col = (t & 15) << 3;
    *(uint4*)&Wlds[row * WPAD + col] = *(const uint4*)&wk[row * C + col];
  }
  __syncthreads();
  const int wave = tid >> 6;
  const int lane = tid & 63;
  const int l15 = lane & 15;
  const int kg = lane >> 4;
  const int pair0 = pairBase + wave * 16;
  const int prA = pair0 + l15;
  const int inIdx = (prA < N_PAIRS) ? in_map[k * N_PAIRS + prA] : 0;
  const unsigned short* arow = xb + (size_t)inIdx * C + kg * 8;
  floatx4 acc[8];
#pragma unroll
  for (int nt = 0; nt < 8; ++nt) acc[nt] = (floatx4){0.f, 0.f, 0.f, 0.f};
#pragma unroll
  for (int kk = 0; kk < 4; ++kk) {
    short8 a = *(const short8*)(arow + kk * 32);
    const unsigned short* bbase = &Wlds[l15 * WPAD + kk * 32 + kg * 8];
#pragma unroll
    for (int nt = 0; nt < 8; ++nt) {
      short8 b = *(const short8*)(bbase + nt * 16 * WPAD);
      acc[nt] = __builtin_amdgcn_mfma_f32_16x16x32_bf16(a, b, acc[nt], 0, 0, 0);
    }
  }
#pragma unroll
  for (int i = 0; i < 4; ++i) {
    int pr = pair0 + kg * 4 + i;
    if (pr < N_PAIRS) {
      int oi = out_map[k * N_PAIRS + pr];
      float* orow = out + (size_t)oi * C + l15;
#pragma unroll
      for (int nt = 0; nt < 8; ++nt) atomicAdd(orow + nt * 16, acc[nt][i]);
    }
  }
}

extern "C" void kernel_launch(void* const* d_in, const int* in_sizes, int n_in,
                              void* d_out, int out_size, void* d_ws, size_t ws_size,
                              hipStream_t stream) {
  const float* features = (const float*)d_in[0];
  const int* in_map     = (const int*)d_in[1];
  const int* out_map    = (const int*)d_in[2];
  const float* W0       = (const float*)d_in[3];
  const float* b0       = (const float*)d_in[4];
  const float* W1       = (const float*)d_in[5];
  const float* b1       = (const float*)d_in[6];
  float* out = (float*)d_out;

  char* ws = (char*)d_ws;
  unsigned short* xb  = (unsigned short*)(ws);                  // 25,600,000
  unsigned short* x1b = (unsigned short*)(ws + 25600000);       // 25,600,000
  unsigned short* WT0 = (unsigned short*)(ws + 51200000);       //    884,736
  unsigned short* WT1 = (unsigned short*)(ws + 52084736);       //    884,736
  int* countc         = (int*)(ws + 52969472);                  //  2,800,000 (7 x 100K)
  int* startc         = (int*)(ws + 55769472);                  //  2,800,000
  int* cursA          = (int*)(ws + 58569472);                  //  2,800,000
  int* cursB          = (int*)(ws + 61369472);                  //  2,800,000
  int* ccur           = (int*)(ws + 64169472);                  //        128 (pad)
  unsigned short* msg2 = (unsigned short*)(ws + 64169600);      // G * 12,800,000

  const long long MSG_K_BYTES = (long long)N_PAIRS * C * 2;     // 12.8 MB per offset
  long long avail = (long long)ws_size - 64169600LL;
  int G = 0;
  if (avail >= MSG_K_BYTES) {
    long long g = avail / MSG_K_BYTES;
    G = (int)(g > K_OFFSETS ? K_OFFSETS : g);
  }
  int nchunks = (G > 0) ? (K_OFFSETS + G - 1) / G : 0;
  const int use_fused = (G > 0 && nchunks <= NCH_MAX) ? 1 : 0;

  prep_w_kernel<<<(2 * K_OFFSETS * C * C + 255) / 256, 256, 0, stream>>>(W0, W1, WT0, WT1);
  prep_x_kernel<<<(N_POINTS * C / 4 + 255) / 256, 256, 0, stream>>>(
      features, b0, xb, out, use_fused ? 0 : 1);

  if (use_fused) {
    zero_meta_kernel<<<(NCH_MAX * N_POINTS + 255) / 256, 256, 0, stream>>>(countc, ccur);
    count_kernel<<<CSR_GROUPS * CSR_BPG, 256, 0, stream>>>(out_map, countc, N_PAIRS * G);
    {
      dim3 agrid((N_POINTS + 255) / 256, nchunks);
      alloc_kernel<<<agrid, 256, 0, stream>>>(countc, startc, cursA, cursB, ccur);
    }

    for (int layer = 0; layer < 2; ++layer) {
      const unsigned short* xin = layer ? x1b : xb;
      const unsigned short* wt  = layer ? WT1 : WT0;
      const float* bias         = layer ? b1  : b0;
      int* curs                 = layer ? cursB : cursA;
      for (int c = 0; c < nchunks; ++c) {
        int k0 = c * G;
        int Gc = K_OFFSETS - k0 < G ? K_OFFSETS - k0 : G;
        dim3 cgrid((N_PAIRS + 127) / 128, Gc);
        conv_msg_csr_kernel<<<cgrid, 256, 0, stream>>>(
            xin, wt, in_map, out_map, curs + (size_t)c * N_POINTS, msg2, k0);
        int init_mode = (c == 0) ? (layer ? 2 : 1) : 0;
        int fin_mode  = (layer == 0 && c == nchunks - 1) ? 1 : 0;
        gather_csr_kernel<<<N_POINTS / 4, 256, 0, stream>>>(
            msg2, countc + (size_t)c * N_POINTS, startc + (size_t)c * N_POINTS,
            bias, features, out, x1b, init_mode, fin_mode);
      }
    }
  } else {
    dim3 cgrid((N_PAIRS + 63) / 64, K_OFFSETS);
    conv_atomic_kernel<<<cgrid, 256, 0, stream>>>(xb, WT0, in_map, out_map, out);
    mid_kernel<<<(N_POINTS * C / 4 + 255) / 256, 256, 0, stream>>>(features, b1, out, x1b);
    conv_atomic_kernel<<<cgrid, 256, 0, stream>>>(x1b, WT1, in_map, out_map, out);
  }
}

// Round 9
// 671.633 us; speedup vs baseline: 1.2168x; 1.2168x over previous
//
#include <hip/hip_runtime.h>

#define N_POINTS 100000
#define N_PAIRS  50000
#define K_OFFSETS 27
#define C 128
#define WPAD 136   // 128 + 8 bf16 pad; LDS row stride 272B
#define CAP 48     // per-point list capacity; Poisson(13.5), P(>=48) ~ 3e-12

// Point-quarter CSR: 4 quarters of 25K points. Per (h,k) bucket is k-pure and
// contiguous (32-padded) -> conv writes msg linearly; gather reads each point
// ONCE per layer (no k-chunking, no out round-trip). msg region (92 MB) reused
// across h and layers.
#define NQ 4
#define QPTS 25000
#define MSGCAP 360448      // slots per quarter; mean 337.5K + pads, +44 sigma
#define GX 110             // conv blocks per k: 110*128 = 14080 >= cnt_hk (+16 sigma)

// XCD-partitioned build (round-2 proven): group g = blockIdx.x % 8 owns points
// [g*12500,(g+1)*12500); quarter h = g/2 (counter+bucket lines stay in one L2).
#define CSR_GROUPS 8
#define CSR_BPG 128

typedef __attribute__((ext_vector_type(8))) short short8;
typedef __attribute__((ext_vector_type(4))) float floatx4;

__device__ inline unsigned short f2bf(float f) {
  unsigned int u = __float_as_uint(f);
  return (unsigned short)((u + 0x7FFFu + ((u >> 16) & 1u)) >> 16);  // RNE
}
__device__ inline float bf2f(unsigned int lo16) {
  return __uint_as_float(lo16 << 16);
}

// WT[k][d*C + c] = bf16(W[k][c][d])  -- natural order for BOTH layers
__global__ __launch_bounds__(256) void prep_w_kernel(
    const float* __restrict__ W0, const float* __restrict__ W1,
    unsigned short* __restrict__ WT0, unsigned short* __restrict__ WT1) {
  int i = blockIdx.x * 256 + threadIdx.x;
  const int per = K_OFFSETS * C * C;
  if (i >= 2 * per) return;
  const float* W = (i < per) ? W0 : W1;
  unsigned short* WT = (i < per) ? WT0 : WT1;
  int r = (i < per) ? i : i - per;
  int k = r / (C * C);
  int q = r % (C * C);
  int d = q / C;
  int c = q % C;
  WT[k * C * C + d * C + c] = f2bf(W[k * C * C + c * C + d]);
}

// xb = bf16(features); out = broadcast(b0) only on the fallback path
__global__ __launch_bounds__(256) void prep_x_kernel(
    const float* __restrict__ features, const float* __restrict__ b0,
    unsigned short* __restrict__ xb, float* __restrict__ out, int write_out) {
  int i = (blockIdx.x * 256 + threadIdx.x) * 4;
  if (i >= N_POINTS * C) return;
  float4 f = *(const float4*)&features[i];
  ushort4 u;
  u.x = f2bf(f.x); u.y = f2bf(f.y); u.z = f2bf(f.z); u.w = f2bf(f.w);
  *(ushort4*)&xb[i] = u;
  if (write_out) {
    float4 b = *(const float4*)&b0[i & 127];
    *(float4*)&out[i] = b;
  }
}

__global__ __launch_bounds__(256) void zero_meta_kernel(
    int* __restrict__ counts, int* __restrict__ counts_hk) {
  int i = blockIdx.x * 256 + threadIdx.x;
  if (i < N_POINTS) counts[i] = 0;
  if (i < NQ * K_OFFSETS) counts_hk[i] = 0;
}

// Pass 1: per-(quarter,k) totals. LDS histogram, 108 global atomics per block.
// 50000 % 4 == 0, so the 4 packed entries share k.
__global__ __launch_bounds__(256) void count_hk_kernel(
    const int* __restrict__ out_map, int* __restrict__ counts_hk) {
  __shared__ int hist[NQ * K_OFFSETS];
  if (threadIdx.x < NQ * K_OFFSETS) hist[threadIdx.x] = 0;
  __syncthreads();
  const int total4 = K_OFFSETS * N_PAIRS / 4;
  for (int i4 = blockIdx.x * 256 + (int)threadIdx.x; i4 < total4; i4 += 256 * 256) {
    int4 o4 = *(const int4*)&out_map[i4 * 4];
    int o[4] = {o4.x, o4.y, o4.z, o4.w};
    int k = (i4 * 4) / N_PAIRS;
#pragma unroll
    for (int j = 0; j < 4; ++j) atomicAdd(&hist[(o[j] / QPTS) * K_OFFSETS + k], 1);
  }
  __syncthreads();
  if (threadIdx.x < NQ * K_OFFSETS)
    atomicAdd(&counts_hk[threadIdx.x], hist[threadIdx.x]);
}

// Pass 2: exclusive scan of 32-padded bucket sizes, per quarter (bases reset to 0
// each h -- msg region is reused per quarter). cursor = live alloc cursor.
__global__ void scan_kernel(const int* __restrict__ counts_hk,
                            int* __restrict__ base_hk, int* __restrict__ cursor_hk) {
  if (threadIdx.x < NQ) {
    int h = threadIdx.x;
    int run = 0;
    for (int k = 0; k < K_OFFSETS; ++k) {
      base_hk[h * K_OFFSETS + k] = run;
      cursor_hk[h * K_OFFSETS + k] = run;
      run += (counts_hk[h * K_OFFSETS + k] + 31) & ~31;
    }
  }
}

// Pass 3: slot assignment + per-point lists. Two-level alloc: block LDS hist ->
// one cursor atomicAdd per (block,k) -> per-element LDS position. pairlist is
// per-quarter (h*MSGCAP + slot). idxbuf[o*CAP+pos] = h-local slot.
__global__ __launch_bounds__(256) void build2_kernel(
    const int* __restrict__ out_map, const int* __restrict__ in_map,
    int* __restrict__ counts, int* __restrict__ idxbuf,
    int* __restrict__ cursor_hk, int* __restrict__ pairlist) {
  __shared__ int histA[K_OFFSETS];
  __shared__ int kbase[K_OFFSETS];
  const int grp = blockIdx.x & (CSR_GROUPS - 1);
  const int blk = blockIdx.x >> 3;
  const int h = grp >> 1;
  const int lo = grp * (N_POINTS / CSR_GROUPS);
  const int hi = lo + (N_POINTS / CSR_GROUPS);
  if (threadIdx.x < K_OFFSETS) histA[threadIdx.x] = 0;
  __syncthreads();
  const int total4 = K_OFFSETS * N_PAIRS / 4;
  for (int i4 = blk * 256 + (int)threadIdx.x; i4 < total4; i4 += CSR_BPG * 256) {
    int4 o4 = *(const int4*)&out_map[i4 * 4];
    int o[4] = {o4.x, o4.y, o4.z, o4.w};
    int k = (i4 * 4) / N_PAIRS;
#pragma unroll
    for (int j = 0; j < 4; ++j)
      if (o[j] >= lo && o[j] < hi) atomicAdd(&histA[k], 1);
  }
  __syncthreads();
  if (threadIdx.x < K_OFFSETS) {
    kbase[threadIdx.x] =
        atomicAdd(&cursor_hk[h * K_OFFSETS + threadIdx.x], histA[threadIdx.x]);
    histA[threadIdx.x] = 0;
  }
  __syncthreads();
  for (int i4 = blk * 256 + (int)threadIdx.x; i4 < total4; i4 += CSR_BPG * 256) {
    int4 o4 = *(const int4*)&out_map[i4 * 4];
    int4 n4 = *(const int4*)&in_map[i4 * 4];
    int o[4] = {o4.x, o4.y, o4.z, o4.w};
    int n[4] = {n4.x, n4.y, n4.z, n4.w};
    int k = (i4 * 4) / N_PAIRS;
#pragma unroll
    for (int j = 0; j < 4; ++j) {
      if (o[j] >= lo && o[j] < hi) {
        int pk = atomicAdd(&histA[k], 1);
        int slot = kbase[k] + pk;
        pairlist[h * MSGCAP + slot] = n[j];
        int pos = atomicAdd(&counts[o[j]], 1);
        if (pos < CAP) idxbuf[o[j] * CAP + pos] = slot;
      }
    }
  }
}

// Conv (quarter h): grid (GX, 27); wave handles 32 contiguous slots = 2 A-tiles.
// pairlist read coalesced, msg writes LINEAR (slots contiguous), W from LDS --
// the exact baseline MFMA core. Pad slots (cnt..cpad) compute garbage from a
// masked index (any masked idx*256 stays inside ws) and are never gathered.
__global__ __launch_bounds__(256, 4) void conv2_kernel(
    const unsigned short* __restrict__ xin, const unsigned short* __restrict__ wbt,
    const int* __restrict__ counts_hk, const int* __restrict__ base_hk,
    const int* __restrict__ pairlist, unsigned short* __restrict__ msg2, int h) {
  __shared__ unsigned short Wlds[C * WPAD];
  const int k = blockIdx.y;
  const int cnt = counts_hk[h * K_OFFSETS + k];
  const int cpad = (cnt + 31) & ~31;
  const int off0 = blockIdx.x * 128;
  if (off0 >= cpad) return;            // block-uniform, before any barrier
  const int kb = base_hk[h * K_OFFSETS + k];
  const int tid = threadIdx.x;

  const unsigned short* wk = wbt + k * C * C;
#pragma unroll
  for (int it = 0; it < 8; ++it) {
    int t = tid + it * 256;
    int row = t >> 4;
    int col = (t & 15) << 3;
    *(uint4*)&Wlds[row * WPAD + col] = *(const uint4*)&wk[row * C + col];
  }
  __syncthreads();

  const int wave = tid >> 6;
  const int lane = tid & 63;
  const int l15 = lane & 15;
  const int kg = lane >> 4;
  const int ws0 = off0 + wave * 32;
  if (ws0 >= cpad) return;             // wave-uniform (32-aligned windows)

  const int s0 = kb + ws0;
  const int plbase = h * MSGCAP;
  const int n0 = pairlist[plbase + s0 + l15] & 0x1FFFF;
  const int n1 = pairlist[plbase + s0 + 16 + l15] & 0x1FFFF;
  const unsigned short* arow0 = xin + (size_t)n0 * C + kg * 8;
  const unsigned short* arow1 = xin + (size_t)n1 * C + kg * 8;

  floatx4 acc0[8], acc1[8];
#pragma unroll
  for (int nt = 0; nt < 8; ++nt) {
    acc0[nt] = (floatx4){0.f, 0.f, 0.f, 0.f};
    acc1[nt] = (floatx4){0.f, 0.f, 0.f, 0.f};
  }
#pragma unroll
  for (int kk = 0; kk < 4; ++kk) {
    short8 a0 = *(const short8*)(arow0 + kk * 32);
    short8 a1 = *(const short8*)(arow1 + kk * 32);
    const unsigned short* bbase = &Wlds[l15 * WPAD + kk * 32 + kg * 8];
#pragma unroll
    for (int nt = 0; nt < 8; ++nt) {
      short8 b = *(const short8*)(bbase + nt * 16 * WPAD);
      acc0[nt] = __builtin_amdgcn_mfma_f32_16x16x32_bf16(a0, b, acc0[nt], 0, 0, 0);
      acc1[nt] = __builtin_amdgcn_mfma_f32_16x16x32_bf16(a1, b, acc1[nt], 0, 0, 0);
    }
  }
#pragma unroll
  for (int i = 0; i < 4; ++i) {
    {
      unsigned short* row = msg2 + (size_t)(s0 + kg * 4 + i) * C;
      uint4 v;
      v.x = (unsigned int)f2bf(acc0[0][i]) | ((unsigned int)f2bf(acc0[1][i]) << 16);
      v.y = (unsigned int)f2bf(acc0[2][i]) | ((unsigned int)f2bf(acc0[3][i]) << 16);
      v.z = (unsigned int)f2bf(acc0[4][i]) | ((unsigned int)f2bf(acc0[5][i]) << 16);
      v.w = (unsigned int)f2bf(acc0[6][i]) | ((unsigned int)f2bf(acc0[7][i]) << 16);
      *(uint4*)(row + l15 * 8) = v;
    }
    {
      unsigned short* row = msg2 + (size_t)(s0 + 16 + kg * 4 + i) * C;
      uint4 v;
      v.x = (unsigned int)f2bf(acc1[0][i]) | ((unsigned int)f2bf(acc1[1][i]) << 16);
      v.y = (unsigned int)f2bf(acc1[2][i]) | ((unsigned int)f2bf(acc1[3][i]) << 16);
      v.z = (unsigned int)f2bf(acc1[4][i]) | ((unsigned int)f2bf(acc1[5][i]) << 16);
      v.w = (unsigned int)f2bf(acc1[6][i]) | ((unsigned int)f2bf(acc1[7][i]) << 16);
      *(uint4*)(row + l15 * 8) = v;
    }
  }
}

// Gather (quarter h): one wave per point, ONE pass over all 27 k. Dense slot
// list (no ballot/filter). layer 0: x1b = bf16(relu(b0 + sum));
// layer 1: out = b1 + features + sum. No out round-trip anywhere.
__global__ __launch_bounds__(256) void gather2_kernel(
    const unsigned short* __restrict__ msg2, const int* __restrict__ counts,
    const int* __restrict__ idxbuf, const float* __restrict__ bias,
    const float* __restrict__ features, float* __restrict__ out,
    unsigned short* __restrict__ x1b, int h, int layer) {
  __shared__ int elds[4][64];
  const int wave = threadIdx.x >> 6;
  const int lane = threadIdx.x & 63;
  const int oi = h * QPTS + blockIdx.x * 4 + wave;

  const int c0 = ((2 * lane) & 7) * 16 + (lane >> 2);
  const int c1 = c0 + 16;
  const size_t base = (size_t)oi * C;

  float a0, a1;
  if (layer == 0) { a0 = bias[c0]; a1 = bias[c1]; }
  else            { a0 = bias[c0] + features[base + c0];
                    a1 = bias[c1] + features[base + c1]; }

  int cnt = counts[oi]; if (cnt > CAP) cnt = CAP;
  if (lane < cnt) elds[wave][lane] = idxbuf[oi * CAP + lane];
  __syncthreads();

  const unsigned short* mb = msg2 + 2 * lane;
  int t = 0;
  for (; t + 4 <= cnt; t += 4) {
    int f0 = elds[wave][t];
    int f1 = elds[wave][t + 1];
    int f2 = elds[wave][t + 2];
    int f3 = elds[wave][t + 3];
    unsigned int v0 = *(const unsigned int*)(mb + (size_t)f0 * C);
    unsigned int v1 = *(const unsigned int*)(mb + (size_t)f1 * C);
    unsigned int v2 = *(const unsigned int*)(mb + (size_t)f2 * C);
    unsigned int v3 = *(const unsigned int*)(mb + (size_t)f3 * C);
    a0 += bf2f(v0 & 0xffffu) + bf2f(v1 & 0xffffu) + bf2f(v2 & 0xffffu) + bf2f(v3 & 0xffffu);
    a1 += bf2f(v0 >> 16) + bf2f(v1 >> 16) + bf2f(v2 >> 16) + bf2f(v3 >> 16);
  }
  for (; t < cnt; ++t) {
    int f0 = elds[wave][t];
    unsigned int v = *(const unsigned int*)(mb + (size_t)f0 * C);
    a0 += bf2f(v & 0xffffu);
    a1 += bf2f(v >> 16);
  }

  if (layer == 0) {
    x1b[base + c0] = f2bf(fmaxf(a0, 0.f));
    x1b[base + c1] = f2bf(fmaxf(a1, 0.f));
  } else {
    out[base + c0] = a0;
    out[base + c1] = a1;
  }
}

// ---------------- fallback (atomic path, small ws, natural WT) ----------------
__global__ __launch_bounds__(256) void mid_kernel(
    const float* __restrict__ features, const float* __restrict__ b1,
    float* __restrict__ out, unsigned short* __restrict__ x1b) {
  int i = (blockIdx.x * 256 + threadIdx.x) * 4;
  if (i >= N_POINTS * C) return;
  float4 y = *(const float4*)&out[i];
  ushort4 u;
  u.x = f2bf(fmaxf(y.x, 0.f));
  u.y = f2bf(fmaxf(y.y, 0.f));
  u.z = f2bf(fmaxf(y.z, 0.f));
  u.w = f2bf(fmaxf(y.w, 0.f));
  *(ushort4*)&x1b[i] = u;
  float4 f = *(const float4*)&features[i];
  float4 b = *(const float4*)&b1[i & 127];
  float4 o;
  o.x = f.x + b.x; o.y = f.y + b.y; o.z = f.z + b.z; o.w = f.w + b.w;
  *(float4*)&out[i] = o;
}

__global__ __launch_bounds__(256, 4) void conv_atomic_kernel(
    const unsigned short* __restrict__ xb, const unsigned short* __restrict__ wbt,
    const int* __restrict__ in_map, const int* __restrict__ out_map,
    float* __restrict__ out) {
  __shared__ unsigned short Wlds[C * WPAD];
  const int k = blockIdx.y;
  const int pairBase = blockIdx.x * 64;
  const int tid = threadIdx.x;
  const unsigned short* wk = wbt + k * C * C;
#pragma unroll
  for (int it = 0; it < 8; ++it) {
    int t = tid + it * 256;
    int row = t >> 4;
    int col = (t & 15) << 3;
    *(uint4*)&Wlds[row * WPAD + col] = *(const uint4*)&wk[row * C + col];
  }
  __syncthreads();
  const int wave = tid >> 6;
  const int lane = tid & 63;
  const int l15 = lane & 15;
  const int kg = lane >> 4;
  const int pair0 = pairBase + wave * 16;
  const int prA = pair0 + l15;
  const int inIdx = (prA < N_PAIRS) ? in_map[k * N_PAIRS + prA] : 0;
  const unsigned short* arow = xb + (size_t)inIdx * C + kg * 8;
  floatx4 acc[8];
#pragma unroll
  for (int nt = 0; nt < 8; ++nt) acc[nt] = (floatx4){0.f, 0.f, 0.f, 0.f};
#pragma unroll
  for (int kk = 0; kk < 4; ++kk) {
    short8 a = *(const short8*)(arow + kk * 32);
    const unsigned short* bbase = &Wlds[l15 * WPAD + kk * 32 + kg * 8];
#pragma unroll
    for (int nt = 0; nt < 8; ++nt) {
      short8 b = *(const short8*)(bbase + nt * 16 * WPAD);
      acc[nt] = __builtin_amdgcn_mfma_f32_16x16x32_bf16(a, b, acc[nt], 0, 0, 0);
    }
  }
#pragma unroll
  for (int i = 0; i < 4; ++i) {
    int pr = pair0 + kg * 4 + i;
    if (pr < N_PAIRS) {
      int oi = out_map[k * N_PAIRS + pr];
      float* orow = out + (size_t)oi * C + l15;
#pragma unroll
      for (int nt = 0; nt < 8; ++nt) atomicAdd(orow + nt * 16, acc[nt][i]);
    }
  }
}

extern "C" void kernel_launch(void* const* d_in, const int* in_sizes, int n_in,
                              void* d_out, int out_size, void* d_ws, size_t ws_size,
                              hipStream_t stream) {
  const float* features = (const float*)d_in[0];
  const int* in_map     = (const int*)d_in[1];
  const int* out_map    = (const int*)d_in[2];
  const float* W0       = (const float*)d_in[3];
  const float* b0       = (const float*)d_in[4];
  const float* W1       = (const float*)d_in[5];
  const float* b1       = (const float*)d_in[6];
  float* out = (float*)d_out;

  char* ws = (char*)d_ws;
  unsigned short* xb  = (unsigned short*)(ws);                  // 25,600,000
  unsigned short* x1b = (unsigned short*)(ws + 25600000);       // 25,600,000
  unsigned short* WT0 = (unsigned short*)(ws + 51200000);       //    884,736
  unsigned short* WT1 = (unsigned short*)(ws + 52084736);       //    884,736
  int* counts         = (int*)(ws + 52969472);                  //    400,384
  int* counts_hk      = (int*)(ws + 53369856);                  //        512
  int* base_hk        = (int*)(ws + 53370368);                  //        512
  int* cursor_hk      = (int*)(ws + 53370880);                  //        512
  int* pairlist       = (int*)(ws + 53371392);                  //  5,767,168 (4 x MSGCAP x 4)
  int* idxbuf         = (int*)(ws + 59138560);                  // 19,200,000 (100000*CAP*4)
  unsigned short* msg2 = (unsigned short*)(ws + 78338560);      // 92,274,688 (MSGCAP*256)
  // end = 170,613,248

  const int use2 = (ws_size >= 170613248ULL) ? 1 : 0;

  prep_w_kernel<<<(2 * K_OFFSETS * C * C + 255) / 256, 256, 0, stream>>>(W0, W1, WT0, WT1);
  prep_x_kernel<<<(N_POINTS * C / 4 + 255) / 256, 256, 0, stream>>>(
      features, b0, xb, out, use2 ? 0 : 1);

  if (use2) {
    zero_meta_kernel<<<(N_POINTS + 255) / 256, 256, 0, stream>>>(counts, counts_hk);
    count_hk_kernel<<<256, 256, 0, stream>>>(out_map, counts_hk);
    scan_kernel<<<1, 64, 0, stream>>>(counts_hk, base_hk, cursor_hk);
    build2_kernel<<<CSR_GROUPS * CSR_BPG, 256, 0, stream>>>(
        out_map, in_map, counts, idxbuf, cursor_hk, pairlist);

    for (int layer = 0; layer < 2; ++layer) {
      const unsigned short* xin = layer ? x1b : xb;
      const unsigned short* wt  = layer ? WT1 : WT0;
      const float* bias         = layer ? b1  : b0;
      for (int h = 0; h < NQ; ++h) {
        dim3 cgrid(GX, K_OFFSETS);
        conv2_kernel<<<cgrid, 256, 0, stream>>>(
            xin, wt, counts_hk, base_hk, pairlist, msg2, h);
        gather2_kernel<<<QPTS / 4, 256, 0, stream>>>(
            msg2, counts, idxbuf, bias, features, out, x1b, h, layer);
      }
    }
  } else {
    dim3 cgrid((N_PAIRS + 63) / 64, K_OFFSETS);
    conv_atomic_kernel<<<cgrid, 256, 0, stream>>>(xb, WT0, in_map, out_map, out);
    mid_kernel<<<(N_POINTS * C / 4 + 255) / 256, 256, 0, stream>>>(features, b1, out, x1b);
    conv_atomic_kernel<<<cgrid, 256, 0, stream>>>(x1b, WT1, in_map, out_map, out);
  }
}